// Round 3
// baseline (90.486 us; speedup 1.0000x reference)
//
#include <hip/hip_runtime.h>
#include <math.h>

#define BATCH 131072
#define EPS 1e-8f

// ws layout (floats):
// [0..255]        logw (16x16, [j][0]=0)
// [256]           alpha = logdet(L0 + I)
// [512..16895]    S8 table: per hi-mask h (bits 8..15), 8x8 Schur complement (64 floats)
// [17408..17663]  partial logdet per hi-mask h (pivots of vars 8..15)

// Stage A: 5 blocks x 64 threads (proven round-1 kernel, unchanged).
// Thread tg in [0,256): hi-mask task. tg==256: alpha task.
// tg in [288,304): log-softmax rows of W.
__global__ __launch_bounds__(64, 1) void stageA_kernel(const float* __restrict__ W,
                                                       const float* __restrict__ A,
                                                       const float* __restrict__ Bm,
                                                       const float* __restrict__ Cm,
                                                       float* __restrict__ ws) {
    __shared__ float sL0[256];
    int lt = threadIdx.x;
    #pragma unroll
    for (int q = 0; q < 4; ++q) {
        int e = lt * 4 + q;
        int i = e >> 4, j = e & 15;
        float s = 0.f;
        #pragma unroll
        for (int k = 0; k < 16; ++k) {
            s += A[k * 16 + i] * A[k * 16 + j];      // (A^T A)[i][j]
            s += Bm[i * 16 + k] * Cm[j * 16 + k]     // (B C^T)[i][j]
               - Cm[i * 16 + k] * Bm[j * 16 + k];    // (C B^T)[i][j]
        }
        if (i == j) s += EPS;
        sL0[e] = s;
    }
    __syncthreads();

    unsigned tg = blockIdx.x * 64u + (unsigned)lt;

    if (tg >= 288u && tg < 304u) {
        int r = (int)tg - 288;
        float row[15];
        float mx = -1e30f;
        #pragma unroll
        for (int q = 0; q < 15; ++q) { row[q] = W[r * 15 + q]; mx = fmaxf(mx, row[q]); }
        float se = 0.f;
        #pragma unroll
        for (int q = 0; q < 15; ++q) se += expf(row[q] - mx);
        float lse = mx + logf(se);
        ws[r * 16 + 0] = 0.f;
        #pragma unroll
        for (int q = 0; q < 15; ++q) ws[r * 16 + 1 + q] = row[q] - lse;
    }

    if (tg > 256u) return;
    bool isAlpha = (tg == 256u);
    unsigned h = isAlpha ? 0xFFu : tg;

    // Permuted order P = [8..15, 0..7]: eliminate vars 8..15 first.
    float a[16][16];
    #pragma unroll
    for (int r = 0; r < 16; ++r) {
        int i = (r < 8) ? (8 + r) : (r - 8);
        bool pi = (i < 8) ? true : (((h >> (i - 8)) & 1u) != 0u);
        #pragma unroll
        for (int c = 0; c < 16; ++c) {
            int j = (c < 8) ? (8 + c) : (c - 8);
            bool pj = (j < 8) ? true : (((h >> (j - 8)) & 1u) != 0u);
            float v = (pi && pj) ? sL0[i * 16 + j] : ((r == c) ? 1.f : 0.f);
            if (isAlpha && r == c) v += 1.f;      // L0 + I
            a[r][c] = v;
        }
    }

    float plog = 0.f;
    #pragma unroll
    for (int k = 0; k < 8; ++k) {
        float piv = a[k][k];
        plog += __logf(fabsf(piv));
        float inv = 1.0f / piv;
        #pragma unroll
        for (int r2 = k + 1; r2 < 16; ++r2) {
            float f = a[r2][k] * inv;
            #pragma unroll
            for (int c2 = k + 1; c2 < 16; ++c2)
                a[r2][c2] = fmaf(-f, a[k][c2], a[r2][c2]);
        }
    }

    if (!isAlpha) {
        #pragma unroll
        for (int i = 0; i < 8; ++i)
            #pragma unroll
            for (int j = 0; j < 8; ++j)
                ws[512 + h * 64 + i * 8 + j] = a[8 + i][8 + j];
        ws[17408 + h] = plog;
    } else {
        #pragma unroll
        for (int k = 8; k < 16; ++k) {
            float piv = a[k][k];
            plog += __logf(fabsf(piv));
            float inv = 1.0f / piv;
            #pragma unroll
            for (int r2 = k + 1; r2 < 16; ++r2) {
                float f = a[r2][k] * inv;
                #pragma unroll
                for (int c2 = k + 1; c2 < 16; ++c2)
                    a[r2][c2] = fmaf(-f, a[k][c2], a[r2][c2]);
            }
        }
        ws[256] = plog;
    }
}

// Main: one thread per sample. Decode bits -> lw + mask, gather the hi-mask's
// 8x8 Schur row (L2-hot, 64 KB table), masked 8x8 register LU (64 floats,
// no spill), write result. stageB is gone: one fewer dispatch + gap.
__global__ __launch_bounds__(256) void main_kernel(const int4* __restrict__ x,
                                                   const float* __restrict__ ws,
                                                   float* __restrict__ out) {
    __shared__ float slw[256];
    __shared__ float sAlpha;
    int lt = threadIdx.x;
    slw[lt] = ws[lt];
    if (lt == 0) sAlpha = ws[256];
    __syncthreads();

    int g = blockIdx.x * 256 + lt;
    const int4* xb = x + (size_t)g * 16;

    float lw = 0.f;
    unsigned mask = 0;
    #pragma unroll
    for (int j = 0; j < 16; ++j) {
        int4 v = xb[j];                              // 4 bits of part j
        int idx = v.x + 2 * v.y + 4 * v.z + 8 * v.w; // 0..15
        lw += slw[j * 16 + idx];                     // logw[j][0]==0
        mask |= (idx != 0 ? 1u : 0u) << j;
    }
    const unsigned h2 = mask >> 8;
    const unsigned lo = mask & 255u;

    // load this hi-mask's 8x8 Schur (256 B)
    const float4* S4 = (const float4*)(ws + 512 + (size_t)h2 * 64);
    float a[8][8];
    #pragma unroll
    for (int i = 0; i < 16; ++i) {
        const float4 q4 = S4[i];
        const int ri = i >> 1, cb = (i & 1) * 4;
        a[ri][cb + 0] = q4.x; a[ri][cb + 1] = q4.y;
        a[ri][cb + 2] = q4.z; a[ri][cb + 3] = q4.w;
    }
    #pragma unroll
    for (int i = 0; i < 8; ++i) {
        const bool bi = ((lo >> i) & 1u) != 0u;
        #pragma unroll
        for (int j = 0; j < 8; ++j) {
            const bool bj = ((lo >> j) & 1u) != 0u;
            if (!(bi && bj)) a[i][j] = (i == j) ? 1.f : 0.f;
        }
    }

    float ld = ws[17408 + h2] + lw - sAlpha;
    #pragma unroll
    for (int k = 0; k < 8; ++k) {
        const float piv = a[k][k];
        ld += __logf(fabsf(piv));
        const float inv = 1.0f / piv;
        #pragma unroll
        for (int i = k + 1; i < 8; ++i) {
            const float f = a[i][k] * inv;
            #pragma unroll
            for (int j = k + 1; j < 8; ++j)
                a[i][j] = fmaf(-f, a[k][j], a[i][j]);
        }
    }
    out[g] = ld;
}

extern "C" void kernel_launch(void* const* d_in, const int* in_sizes, int n_in,
                              void* d_out, int out_size, void* d_ws, size_t ws_size,
                              hipStream_t stream) {
    const float* W = (const float*)d_in[1];
    const float* A = (const float*)d_in[2];
    const float* B = (const float*)d_in[3];
    const float* C = (const float*)d_in[4];
    const int4*  x = (const int4*)d_in[0];
    float* ws  = (float*)d_ws;
    float* out = (float*)d_out;

    stageA_kernel<<<5, 64, 0, stream>>>(W, A, B, C, ws);
    main_kernel<<<BATCH / 256, 256, 0, stream>>>(x, ws, out);
}

// Round 4
// 90.382 us; speedup vs baseline: 1.0011x; 1.0011x over previous
//
#include <hip/hip_runtime.h>
#include <math.h>

#define BATCH 131072
#define EPS 1e-8f

// ws layout (floats):
// [0..255]        logw (16x16, [j][0]=0)
// [256]           alpha = logdet(L0 + I)
// [512..16895]    S8 table: per hi-mask h (bits 8..15), 8x8 Schur complement (64 floats)
// [17408..17663]  partial logdet per hi-mask h (pivots of vars 8..15)

// Stage A: 5 blocks x 64 threads (proven; unchanged).
__global__ __launch_bounds__(64, 1) void stageA_kernel(const float* __restrict__ W,
                                                       const float* __restrict__ A,
                                                       const float* __restrict__ Bm,
                                                       const float* __restrict__ Cm,
                                                       float* __restrict__ ws) {
    __shared__ float sL0[256];
    int lt = threadIdx.x;
    #pragma unroll
    for (int q = 0; q < 4; ++q) {
        int e = lt * 4 + q;
        int i = e >> 4, j = e & 15;
        float s = 0.f;
        #pragma unroll
        for (int k = 0; k < 16; ++k) {
            s += A[k * 16 + i] * A[k * 16 + j];
            s += Bm[i * 16 + k] * Cm[j * 16 + k]
               - Cm[i * 16 + k] * Bm[j * 16 + k];
        }
        if (i == j) s += EPS;
        sL0[e] = s;
    }
    __syncthreads();

    unsigned tg = blockIdx.x * 64u + (unsigned)lt;

    if (tg >= 288u && tg < 304u) {
        int r = (int)tg - 288;
        float row[15];
        float mx = -1e30f;
        #pragma unroll
        for (int q = 0; q < 15; ++q) { row[q] = W[r * 15 + q]; mx = fmaxf(mx, row[q]); }
        float se = 0.f;
        #pragma unroll
        for (int q = 0; q < 15; ++q) se += expf(row[q] - mx);
        float lse = mx + logf(se);
        ws[r * 16 + 0] = 0.f;
        #pragma unroll
        for (int q = 0; q < 15; ++q) ws[r * 16 + 1 + q] = row[q] - lse;
    }

    if (tg > 256u) return;
    bool isAlpha = (tg == 256u);
    unsigned h = isAlpha ? 0xFFu : tg;

    float a[16][16];
    #pragma unroll
    for (int r = 0; r < 16; ++r) {
        int i = (r < 8) ? (8 + r) : (r - 8);
        bool pi = (i < 8) ? true : (((h >> (i - 8)) & 1u) != 0u);
        #pragma unroll
        for (int c = 0; c < 16; ++c) {
            int j = (c < 8) ? (8 + c) : (c - 8);
            bool pj = (j < 8) ? true : (((h >> (j - 8)) & 1u) != 0u);
            float v = (pi && pj) ? sL0[i * 16 + j] : ((r == c) ? 1.f : 0.f);
            if (isAlpha && r == c) v += 1.f;
            a[r][c] = v;
        }
    }

    float plog = 0.f;
    #pragma unroll
    for (int k = 0; k < 8; ++k) {
        float piv = a[k][k];
        plog += __logf(fabsf(piv));
        float inv = 1.0f / piv;
        #pragma unroll
        for (int r2 = k + 1; r2 < 16; ++r2) {
            float f = a[r2][k] * inv;
            #pragma unroll
            for (int c2 = k + 1; c2 < 16; ++c2)
                a[r2][c2] = fmaf(-f, a[k][c2], a[r2][c2]);
        }
    }

    if (!isAlpha) {
        #pragma unroll
        for (int i = 0; i < 8; ++i)
            #pragma unroll
            for (int j = 0; j < 8; ++j)
                ws[512 + h * 64 + i * 8 + j] = a[8 + i][8 + j];
        ws[17408 + h] = plog;
    } else {
        #pragma unroll
        for (int k = 8; k < 16; ++k) {
            float piv = a[k][k];
            plog += __logf(fabsf(piv));
            float inv = 1.0f / piv;
            #pragma unroll
            for (int r2 = k + 1; r2 < 16; ++r2) {
                float f = a[r2][k] * inv;
                #pragma unroll
                for (int c2 = k + 1; c2 < 16; ++c2)
                    a[r2][c2] = fmaf(-f, a[k][c2], a[r2][c2]);
            }
        }
        ws[256] = plog;
    }
}

// Main: wave-transposed coalesced x-read.
// Each wave handles 64 samples = 1024 int4 = 16 KB, read as 16 contiguous
// 1-KB wave transactions (lane-consecutive int4). Item (step, lane) is part
// j = lane&15 of local sample step*4 + (lane>>4). Per step: idx from bits,
// lw contribution via transposed LDS table, 16-lane shfl_xor sum, mask from
// one __ballot. Lane (p=lane&15, gq=lane>>4) keeps step p -> owns sample
// p*4+gq. Then the proven masked 8x8 register LU.
__global__ __launch_bounds__(256) void main_kernel(const int4* __restrict__ x,
                                                   const float* __restrict__ ws,
                                                   float* __restrict__ out) {
    __shared__ float slwT[256];   // transposed: [idx][j]
    __shared__ float sAlpha;
    int lt = threadIdx.x;
    {
        float v = ws[lt];                     // ws[j*16+idx]
        slwT[(lt & 15) * 16 + (lt >> 4)] = v; // -> [idx][j]
    }
    if (lt == 0) sAlpha = ws[256];
    __syncthreads();

    const int lane = lt & 63;
    const int waveInBlk = lt >> 6;                          // 0..3
    const int sampleBase = blockIdx.x * 256 + waveInBlk * 64;
    const int4* xw = x + (size_t)sampleBase * 16;           // wave's 1024 int4

    const int p  = lane & 15;   // part j of my loads; also the step I keep
    const int gq = lane >> 4;   // sample offset within a step

    float lwKeep = 0.f;
    unsigned maskKeep = 0u;
    #pragma unroll
    for (int step = 0; step < 16; ++step) {
        int4 v = xw[step * 64 + lane];                      // coalesced
        int idx = v.x + 2 * v.y + 4 * v.z + 8 * v.w;        // 0..15
        float c = slwT[idx * 16 + p];                       // logw[p][idx]
        unsigned long long bal = __ballot(idx != 0);
        c += __shfl_xor(c, 1, 16);
        c += __shfl_xor(c, 2, 16);
        c += __shfl_xor(c, 4, 16);
        c += __shfl_xor(c, 8, 16);
        if (p == step) {
            lwKeep   = c;
            maskKeep = (unsigned)((bal >> (gq * 16)) & 0xFFFFull);
        }
    }

    const int g = sampleBase + p * 4 + gq;   // my sample
    const unsigned h2 = maskKeep >> 8;
    const unsigned lo = maskKeep & 255u;

    const float4* S4 = (const float4*)(ws + 512 + (size_t)h2 * 64);
    float a[8][8];
    #pragma unroll
    for (int i = 0; i < 16; ++i) {
        const float4 q4 = S4[i];
        const int ri = i >> 1, cb = (i & 1) * 4;
        a[ri][cb + 0] = q4.x; a[ri][cb + 1] = q4.y;
        a[ri][cb + 2] = q4.z; a[ri][cb + 3] = q4.w;
    }
    #pragma unroll
    for (int i = 0; i < 8; ++i) {
        const bool bi = ((lo >> i) & 1u) != 0u;
        #pragma unroll
        for (int j = 0; j < 8; ++j) {
            const bool bj = ((lo >> j) & 1u) != 0u;
            if (!(bi && bj)) a[i][j] = (i == j) ? 1.f : 0.f;
        }
    }

    float ld = ws[17408 + h2] + lwKeep - sAlpha;
    #pragma unroll
    for (int k = 0; k < 8; ++k) {
        const float piv = a[k][k];
        ld += __logf(fabsf(piv));
        const float inv = 1.0f / piv;
        #pragma unroll
        for (int i = k + 1; i < 8; ++i) {
            const float f = a[i][k] * inv;
            #pragma unroll
            for (int j = k + 1; j < 8; ++j)
                a[i][j] = fmaf(-f, a[k][j], a[i][j]);
        }
    }
    out[g] = ld;
}

extern "C" void kernel_launch(void* const* d_in, const int* in_sizes, int n_in,
                              void* d_out, int out_size, void* d_ws, size_t ws_size,
                              hipStream_t stream) {
    const float* W = (const float*)d_in[1];
    const float* A = (const float*)d_in[2];
    const float* B = (const float*)d_in[3];
    const float* C = (const float*)d_in[4];
    const int4*  x = (const int4*)d_in[0];
    float* ws  = (float*)d_ws;
    float* out = (float*)d_out;

    stageA_kernel<<<5, 64, 0, stream>>>(W, A, B, C, ws);
    main_kernel<<<BATCH / 256, 256, 0, stream>>>(x, ws, out);
}